// Round 12
// baseline (149.931 us; speedup 1.0000x reference)
//
#include <hip/hip_runtime.h>
#include <math.h>

#define K_SIZE 5
#define PAD 2
#define DEPTH_MAX 192.0f
#define S_NUM 15
#define G_NUM (K_SIZE * K_SIZE)   // 25

// Fixed problem shape (from reference setup_inputs):
#define B_DIM 2
#define C_DIM 32
#define H_DIM 256
#define W_DIM 512
#define HW (H_DIM * W_DIM)
#define NPX (B_DIM * HW)              // 262144 pixels

// ---- per-wave tile geometry (v7-proven) ----
#define TX 64                  // pixels per block tile (one wave-width)
#define CH_HALF 16             // channels per wave (2 waves x 16 = 32)
#define LROW 80                // LDS row pitch (TX + 16 halo)
#define LDS_F 400              // floats per channel buffer (5 * LROW)
#define NGRP 100               // float4-groups per channel stage
#define CTR_IDX (2 * LROW + 4) // lds float idx of center tap minus lane
#define GPASS 200              // float4 groups per guide half-pass (800 floats)

// ========== Fused v10: 2 waves/block, wave-private, 32 waves/CU ==========
// Cross-round law: the gather loop scales with waves/CU (v4 @32w = 42.5us;
// all @16w = 51-53us), wave-private zero-barrier works (v7), fused weights
// beats the w round-trip (v6). This combines all three:
//  - block = 128 threads = 2 INDEPENDENT waves over the SAME 64-px tile;
//    wave w owns channels [16w, 16w+16) and a private 3.2 KB LDS region
//    (2 x 400-float double buffer, v4-proven depth). ZERO __syncthreads.
//  - 4096 blocks = 16 WG/CU (HW cap) x 2 waves = 32 waves/CU demanded.
//  - phase 0 (weights) runs per-wave (x2 duplication, but the cheap
//    barrier-free v7 version; ~3us device-wide, hidden by TLP).
//  - guide staged wave-privately in two 800-float passes through the
//    same region (half-lanes read each pass).
// Multiply order identical to all proven kernels -> bitwise-identical.
__global__ __launch_bounds__(128) void adaptive_fused_v10(
    const float* __restrict__ depth,      // [B,1,H,W]
    const float* __restrict__ features,   // [B,C,H,W]
    const float* __restrict__ guide,      // [B,H,W,25]
    const int*   __restrict__ sample_idx, // [15]
    float*       __restrict__ out)        // [B,C,H,W] ++ [B,C,H,W] copy
{
    __shared__ float lds_all[2 * 2 * LDS_F];    // [wave][2][400] = 6.4 KB

    const int t    = threadIdx.x;
    const int lane = t & 63;
    const int wv   = t >> 6;                    // 0 or 1
    float* wbase = &lds_all[wv * 2 * LDS_F];    // this wave's private region

    // bijective XCD swizzle: 4096 blocks = 8 XCDs x 512; XCD k owns 64
    // consecutive image rows (halo rows L2-local), b=0 for XCD 0-3, b=1 else.
    const int orig = blockIdx.x;
    const int lid  = (orig & 7) * 512 + (orig >> 3);
    const int tile = lid & 7;                   // 8 x-tiles per row
    const int y    = (lid >> 3) & (H_DIM - 1);
    const int b    = lid >> 11;
    const int x0   = tile * TX;
    const int x    = x0 + lane;                 // this lane's pixel
    const int cw   = wv * CH_HALF;              // wave's channel base

    int sidx[S_NUM];
#pragma unroll
    for (int s = 0; s < S_NUM; ++s) sidx[s] = sample_idx[s];   // uniform

    // ---- staging addresses (v7-proven geometry, per lane) ----
    int soff0, soff1 = 0;
    {
        const int row = lane / 20;
        const int col = (lane - row * 20) * 4;
        int ir = y + row - 2; ir = ir < 0 ? 0 : (ir > H_DIM - 1 ? H_DIM - 1 : ir);
        int ic = x0 - 4 + col; ic = ic < 0 ? 0 : (ic > W_DIM - 4 ? W_DIM - 4 : ic);
        soff0 = ir * W_DIM + ic;
    }
    const bool has2 = (lane < NGRP - 64);       // lanes 0..35: group 64+lane
    if (has2) {
        const int g   = 64 + lane;
        const int row = g / 20;
        const int col = (g - row * 20) * 4;
        int ir = y + row - 2; ir = ir < 0 ? 0 : (ir > H_DIM - 1 ? H_DIM - 1 : ir);
        int ic = x0 - 4 + col; ic = ic < 0 ? 0 : (ic > W_DIM - 4 ? W_DIM - 4 : ic);
        soff1 = ir * W_DIM + ic;
    }
    const int lidx0 = 4 * lane;                 // 0..252
    const int lidx1 = 4 * (64 + lane);          // 256..399 (lanes < 36)

    const size_t hw  = (size_t)HW;
    const float* fpl = features + ((size_t)b * C_DIM + cw) * hw;

    // ---- cross-phase prefetch: wave's ch0 + ch1 issue NOW; all of
    //      phase 0 (guide passes, depth taps, exp) hides their latency ----
    float4 a0, a1, r0, r1;
    a0 = *(const float4*)(fpl + soff0);
    if (has2) a1 = *(const float4*)(fpl + soff1);
    {
        const float* f1 = fpl + hw;
        r0 = *(const float4*)(f1 + soff0);
        if (has2) r1 = *(const float4*)(f1 + soff1);
    }

    // ---------------- phase 0: per-pixel weights (wave-private) ----------
    // gaussian positional weights (uniform math)
    float posw[S_NUM];
    float psum = 0.f;
#pragma unroll
    for (int s = 0; s < S_NUM; ++s) {
        const float px = (float)(sidx[s] % K_SIZE);
        const float py = (float)(sidx[s] / K_SIZE);
        const float ddx = px - (float)(K_SIZE / 2);
        const float ddy = py - (float)(K_SIZE / 2);
        posw[s] = expf(-0.5f * sqrtf(ddx * ddx + ddy * ddy));
        psum += posw[s];
    }
    const float inv_psum = 1.f / psum;

    // pv[s] = v(depth@tap) * normalized posw (same multiply order as ever)
    float pv[S_NUM];
    unsigned inbm = 0;
    const int dbase = b * HW;
#pragma unroll
    for (int s = 0; s < S_NUM; ++s) {
        const int dy = sidx[s] / K_SIZE - PAD;
        const int dx = sidx[s] % K_SIZE - PAD;
        const int yy = y + dy;
        const int xx = x + dx;
        const bool inb = (yy >= 0) & (yy < H_DIM) & (xx >= 0) & (xx < W_DIM);
        float v = 0.f;
        if (inb) {
            const float d = depth[dbase + yy * W_DIM + xx];  // coalesced
            v = (d > 0.f && d < DEPTH_MAX) ? 1.f : 0.f;
        }
        pv[s] = v * (posw[s] * inv_psum);
        inbm |= (unsigned)inb << s;
    }

    // guide in TWO wave-private half-passes through this wave's region:
    // raw[s] = pv[s] * guide_row[sidx[s]]  (order (v*poswn)*g, unchanged)
    float raw[S_NUM];
    const float* gbase = guide + (size_t)(b * HW + y * W_DIM + x0) * G_NUM;
    {
        // pass A: rows for px 0..31 (800 floats = 200 float4), coalesced
        const float4* gsrc = (const float4*)gbase;
        float4* gdst = (float4*)wbase;
#pragma unroll
        for (int k = 0; k < 4; ++k) {
            const int idx = k * 64 + lane;
            if (idx < GPASS) gdst[idx] = gsrc[idx];
        }
        __builtin_amdgcn_wave_barrier();
        if (lane < 32) {
            const float* gr = &wbase[lane * G_NUM];   // stride 25: conflict-free
#pragma unroll
            for (int s = 0; s < S_NUM; ++s) raw[s] = pv[s] * gr[sidx[s]];
        }
        __builtin_amdgcn_wave_barrier();
        // pass B: rows for px 32..63
        const float4* gsrc2 = (const float4*)(gbase + 32 * G_NUM);
#pragma unroll
        for (int k = 0; k < 4; ++k) {
            const int idx = k * 64 + lane;
            if (idx < GPASS) gdst[idx] = gsrc2[idx];
        }
        __builtin_amdgcn_wave_barrier();
        if (lane >= 32) {
            const float* gr = &wbase[(lane - 32) * G_NUM];
#pragma unroll
            for (int s = 0; s < S_NUM; ++s) raw[s] = pv[s] * gr[sidx[s]];
        }
        __builtin_amdgcn_wave_barrier();
    }

    // softmax over the 15 samples (matches jax.nn.softmax exactly)
    float mx = raw[0];
#pragma unroll
    for (int s = 1; s < S_NUM; ++s) mx = fmaxf(mx, raw[s]);
    float esum = 0.f;
    float wgt[S_NUM];
#pragma unroll
    for (int s = 0; s < S_NUM; ++s) {
        wgt[s] = expf(raw[s] - mx);
        esum += wgt[s];
    }
    const float inv_esum = 1.f / esum;
#pragma unroll
    for (int s = 0; s < S_NUM; ++s)
        wgt[s] = wgt[s] * inv_esum * (((inbm >> s) & 1u) ? 1.f : 0.f);

    // tap LDS offsets within a 400-float buffer (max 389 < 400)
    int ldsoff[S_NUM];
#pragma unroll
    for (int s = 0; s < S_NUM; ++s) {
        const int si = sidx[s];
        ldsoff[s] = (si / K_SIZE) * LROW + lane + (si % K_SIZE) + 2;
    }

    // stage wave's ch0 into buf0 (guide passes done; region reuse safe)
    *(float4*)&wbase[lidx0] = a0;
    if (has2) *(float4*)&wbase[lidx1] = a1;
    __builtin_amdgcn_wave_barrier();

    float* o0 = out + ((size_t)b * C_DIM + cw) * hw + (size_t)y * W_DIM + x0 + lane;
    float* o1 = o0 + (size_t)B_DIM * C_DIM * hw;

    // ---- main loop (v4-depth double buffer, wave-private, no s_barrier):
    //      write(c+1) | issue load(c+2) | compute(c) ----
#pragma unroll
    for (int c = 0; c < CH_HALF; ++c) {
        if (c + 1 < CH_HALF) {                    // compile-time (full unroll)
            float* dst = wbase + ((c + 1) & 1) * LDS_F;
            *(float4*)&dst[lidx0] = r0;
            if (has2) *(float4*)&dst[lidx1] = r1;
        }
        float4 t0, t1;
        if (c + 2 < CH_HALF) {
            const float* fn = fpl + (size_t)(c + 2) * hw;
            t0 = *(const float4*)(fn + soff0);
            if (has2) t1 = *(const float4*)(fn + soff1);
        }
        __builtin_amdgcn_wave_barrier();          // writes ordered before reads

        const float* src = wbase + (c & 1) * LDS_F;
        float acc = 0.f;
#pragma unroll
        for (int s = 0; s < S_NUM; ++s)
            acc = fmaf(src[ldsoff[s]], wgt[s], acc);
        const float ctr = src[CTR_IDX + lane];    // exact center value

        o0[(size_t)c * hw] = acc;                 // coalesced stores
        o1[(size_t)c * hw] = ctr;

        if (c + 2 < CH_HALF) { r0 = t0; if (has2) r1 = t1; }
        __builtin_amdgcn_wave_barrier();          // keep iterations ordered
    }
}

extern "C" void kernel_launch(void* const* d_in, const int* in_sizes, int n_in,
                              void* d_out, int out_size, void* d_ws, size_t ws_size,
                              hipStream_t stream) {
    const float* depth      = (const float*)d_in[0];
    const float* features   = (const float*)d_in[1];
    const float* guide      = (const float*)d_in[2];
    const int*   sample_idx = (const int*)d_in[3];

    float* out = (float*)d_out;
    const int blocks = NPX / TX;  // 4096

    adaptive_fused_v10<<<blocks, 128, 0, stream>>>(depth, features, guide,
                                                   sample_idx, out);
}

// Round 13
// 144.773 us; speedup vs baseline: 1.0356x; 1.0356x over previous
//
#include <hip/hip_runtime.h>
#include <math.h>

#define K_SIZE 5
#define PAD 2
#define DEPTH_MAX 192.0f
#define S_NUM 15
#define G_NUM (K_SIZE * K_SIZE)   // 25

// Fixed problem shape (from reference setup_inputs):
#define B_DIM 2
#define C_DIM 32
#define H_DIM 256
#define W_DIM 512
#define HW (H_DIM * W_DIM)
#define NPX (B_DIM * HW)              // 262144 pixels

// ---- tile geometry (v6-proven) ----
#define TX 256                 // pixels per block (half an image row)
#define CH_PER 16              // channels per block (grid.y = 2)
#define LROW 272               // LDS row pitch in floats (TX+16)
#define LDS_F (5 * LROW)       // 1360 floats per channel buffer
#define NGRP (5 * 68)          // 340 float4-groups per channel stage
#define CTR_IDX (2 * LROW + 4) // lds float idx of center tap minus t
#define WREG 1020              // float stride of wave-private guide region

// ========= Fused v11: v6 body at 8 blocks/CU, wave-private phase 0 ========
// Cross-round facts: (1) the staged loop runs 42.5us at 8 blocks/CU (v4)
// vs 51-53us at 4 (v6/v7); (2) phase-0 must be barrier-free and executed
// once per pixel (v9's 5-sync phase-0 cost 6us; v10's per-wave duplication
// cost 25us); (3) fused weights beat the w round-trip (v6 > v4 overall).
// v11 = v6's exact loop + grid (1024,2) (2048 blocks -> 8 blocks/CU) with
// phase-0 done v6-style (wave-private, barrier-free) but staged in two
// 800-float passes through the wave's 4KB slice of sbuf, so block LDS
// stays 16.32 KB (v6's 25.6 KB capped residency). Multiply order
// unchanged -> bitwise-identical output.
__global__ __launch_bounds__(256) void adaptive_fused_v11(
    const float* __restrict__ depth,      // [B,1,H,W]
    const float* __restrict__ features,   // [B,C,H,W]
    const float* __restrict__ guide,      // [B,H,W,25]
    const int*   __restrict__ sample_idx, // [15]
    float*       __restrict__ out)        // [B,C,H,W] ++ [B,C,H,W] copy
{
    __shared__ float lds_raw[3 * LDS_F];        // 4080 floats = 16.32 KB
    float (*sbuf)[LDS_F] = reinterpret_cast<float (*)[LDS_F]>(lds_raw);

    const int t    = threadIdx.x;
    const int lane = t & 63;
    const int wv   = t >> 6;

    // bijective XCD swizzle: 1024 x-ids = 8 XCDs x 128 -> each XCD owns 64
    // consecutive image rows (halo rows L2-local). grid.y picks channels.
    const int orig = blockIdx.x;
    const int lid  = (orig & 7) * 128 + (orig >> 3);
    const int tile = lid & 1;
    const int y    = (lid >> 1) & (H_DIM - 1);
    const int b    = lid >> 9;
    const int x0   = tile * TX;
    const int x    = x0 + t;                    // this thread's pixel
    const int c0   = blockIdx.y * CH_PER;

    int sidx[S_NUM];
#pragma unroll
    for (int s = 0; s < S_NUM; ++s) sidx[s] = sample_idx[s];   // uniform

    // ---- staging addresses (constant across channels; v6-proven) ----
    int soff0, soff1 = 0;
    int lidx0, lidx1 = 0;
    {
        const int g   = t;
        const int row = g / 68;
        const int col = (g - row * 68) * 4;
        lidx0 = row * LROW + col;
        int ir = y + row - 2; ir = ir < 0 ? 0 : (ir > H_DIM - 1 ? H_DIM - 1 : ir);
        int ic = x0 - 4 + col; ic = ic < 0 ? 0 : (ic > W_DIM - 4 ? W_DIM - 4 : ic);
        soff0 = ir * W_DIM + ic;
    }
    const bool has2 = (t < NGRP - 256);          // threads 0..83 stage group 2
    if (has2) {
        const int g   = 256 + t;
        const int row = g / 68;
        const int col = (g - row * 68) * 4;
        lidx1 = row * LROW + col;
        int ir = y + row - 2; ir = ir < 0 ? 0 : (ir > H_DIM - 1 ? H_DIM - 1 : ir);
        int ic = x0 - 4 + col; ic = ic < 0 ? 0 : (ic > W_DIM - 4 ? W_DIM - 4 : ic);
        soff1 = ir * W_DIM + ic;
    }

    const size_t hw  = (size_t)HW;
    const float* fpl = features + ((size_t)b * C_DIM + c0) * hw;

    // ---- cross-phase prefetch: ch0 + ch1 issue NOW; all of phase 0
    //      (guide passes, depth taps, exp math) hides their latency ----
    float4 a0, a1, r0, r1;
    a0 = *(const float4*)(fpl + soff0);
    if (has2) a1 = *(const float4*)(fpl + soff1);
    {
        const float* f1 = fpl + hw;
        r0 = *(const float4*)(f1 + soff0);
        if (has2) r1 = *(const float4*)(f1 + soff1);
    }

    // ------------- phase 0: per-pixel weights (wave-private) -------------
    // gaussian positional weights (uniform math)
    float posw[S_NUM];
    float psum = 0.f;
#pragma unroll
    for (int s = 0; s < S_NUM; ++s) {
        const float px = (float)(sidx[s] % K_SIZE);
        const float py = (float)(sidx[s] / K_SIZE);
        const float ddx = px - (float)(K_SIZE / 2);
        const float ddy = py - (float)(K_SIZE / 2);
        posw[s] = expf(-0.5f * sqrtf(ddx * ddx + ddy * ddy));
        psum += posw[s];
    }
    const float inv_psum = 1.f / psum;

    // pv[s] = v(depth@tap) * normalized posw (same multiply order as ever)
    float pv[S_NUM];
    unsigned inbm = 0;
    const int dbase = b * HW;
#pragma unroll
    for (int s = 0; s < S_NUM; ++s) {
        const int dy = sidx[s] / K_SIZE - PAD;
        const int dx = sidx[s] % K_SIZE - PAD;
        const int yy = y + dy;
        const int xx = x + dx;
        const bool inb = (yy >= 0) & (yy < H_DIM) & (xx >= 0) & (xx < W_DIM);
        float v = 0.f;
        if (inb) {
            const float d = depth[dbase + yy * W_DIM + xx];  // coalesced
            v = (d > 0.f && d < DEPTH_MAX) ? 1.f : 0.f;
        }
        pv[s] = v * (posw[s] * inv_psum);
        inbm |= (unsigned)inb << s;
    }

    // guide: wave-private staging in TWO 800-float passes through this
    // wave's 4KB slice of sbuf (only wave_barriers, no __syncthreads).
    // raw[s] = pv[s] * guide_row[sidx[s]]  (order (v*poswn)*g, unchanged)
    float raw[S_NUM];
    {
        float* wreg = &lds_raw[wv * WREG];      // wave-private 1020 floats
        const float* gbase =
            guide + (size_t)(b * HW + y * W_DIM + x0 + wv * 64) * G_NUM;
        // pass A: rows for lanes 0..31 (800 floats = 200 float4), coalesced
        {
            const float4* gsrc = (const float4*)gbase;
            float4* gdst = (float4*)wreg;
#pragma unroll
            for (int k = 0; k < 4; ++k) {
                const int idx = k * 64 + lane;
                if (idx < 200) gdst[idx] = gsrc[idx];
            }
        }
        __builtin_amdgcn_wave_barrier();
        if (lane < 32) {
            const float* gr = &wreg[lane * G_NUM];   // stride 25: conflict-free
#pragma unroll
            for (int s = 0; s < S_NUM; ++s) raw[s] = pv[s] * gr[sidx[s]];
        }
        __builtin_amdgcn_wave_barrier();
        // pass B: rows for lanes 32..63
        {
            const float4* gsrc = (const float4*)(gbase + 32 * G_NUM);
            float4* gdst = (float4*)wreg;
#pragma unroll
            for (int k = 0; k < 4; ++k) {
                const int idx = k * 64 + lane;
                if (idx < 200) gdst[idx] = gsrc[idx];
            }
        }
        __builtin_amdgcn_wave_barrier();
        if (lane >= 32) {
            const float* gr = &wreg[(lane - 32) * G_NUM];
#pragma unroll
            for (int s = 0; s < S_NUM; ++s) raw[s] = pv[s] * gr[sidx[s]];
        }
    }

    // softmax over the 15 samples (matches jax.nn.softmax exactly)
    float mx = raw[0];
#pragma unroll
    for (int s = 1; s < S_NUM; ++s) mx = fmaxf(mx, raw[s]);
    float esum = 0.f;
    float wgt[S_NUM];
#pragma unroll
    for (int s = 0; s < S_NUM; ++s) {
        wgt[s] = expf(raw[s] - mx);
        esum += wgt[s];
    }
    const float inv_esum = 1.f / esum;
#pragma unroll
    for (int s = 0; s < S_NUM; ++s)
        wgt[s] = wgt[s] * inv_esum * (((inbm >> s) & 1u) ? 1.f : 0.f);

    // tap LDS offsets (always in-range: col = t + (si%5) + 2 <= 261 < 272)
    int ldsoff[S_NUM];
#pragma unroll
    for (int s = 0; s < S_NUM; ++s) {
        const int si = sidx[s];
        ldsoff[s] = (si / K_SIZE) * LROW + t + (si % K_SIZE) + 2;
    }

    __syncthreads();                  // ALL waves done with guide regions

    // stage ch0 into buf0 (region reuse now safe)
    *(float4*)&sbuf[0][lidx0] = a0;
    if (has2) *(float4*)&sbuf[0][lidx1] = a1;
    __syncthreads();                  // buf0 ready

    float* o0 = out + ((size_t)b * C_DIM + c0) * hw + (size_t)y * W_DIM + x0 + t;
    float* o1 = o0 + (size_t)B_DIM * C_DIM * hw;

    // ---- main loop (v5/v6-proven): write(c+1) | load(c+2) | compute(c) ----
#pragma unroll
    for (int c = 0; c < CH_PER; ++c) {
        if (c + 1 < CH_PER) {                     // compile-time (full unroll)
            float* dst = sbuf[(c + 1) % 3];
            *(float4*)&dst[lidx0] = r0;
            if (has2) *(float4*)&dst[lidx1] = r1;
        }
        float4 t0, t1;
        if (c + 2 < CH_PER) {
            const float* fn = fpl + (size_t)(c + 2) * hw;
            t0 = *(const float4*)(fn + soff0);
            if (has2) t1 = *(const float4*)(fn + soff1);
        }

        const float* src = sbuf[c % 3];
        float acc = 0.f;
#pragma unroll
        for (int s = 0; s < S_NUM; ++s)
            acc = fmaf(src[ldsoff[s]], wgt[s], acc);
        const float ctr = src[CTR_IDX + t];       // exact center value

        o0[(size_t)c * hw] = acc;                 // coalesced stores
        o1[(size_t)c * hw] = ctr;

        if (c + 2 < CH_PER) { r0 = t0; if (has2) r1 = t1; }
        __syncthreads();                          // buf[(c+1)%3] ready
    }
}

extern "C" void kernel_launch(void* const* d_in, const int* in_sizes, int n_in,
                              void* d_out, int out_size, void* d_ws, size_t ws_size,
                              hipStream_t stream) {
    const float* depth      = (const float*)d_in[0];
    const float* features   = (const float*)d_in[1];
    const float* guide      = (const float*)d_in[2];
    const int*   sample_idx = (const int*)d_in[3];

    float* out = (float*)d_out;
    dim3 grid(NPX / TX, C_DIM / CH_PER, 1);   // (1024, 2) -> 2048 blocks

    adaptive_fused_v11<<<grid, 256, 0, stream>>>(depth, features, guide,
                                                 sample_idx, out);
}

// Round 14
// 136.116 us; speedup vs baseline: 1.1015x; 1.0636x over previous
//
#include <hip/hip_runtime.h>
#include <math.h>

#define K_SIZE 5
#define PAD 2
#define DEPTH_MAX 192.0f
#define S_NUM 15
#define G_NUM (K_SIZE * K_SIZE)   // 25

// Fixed problem shape (from reference setup_inputs):
#define B_DIM 2
#define C_DIM 32
#define H_DIM 256
#define W_DIM 512
#define HW (H_DIM * W_DIM)
#define NPX (B_DIM * HW)              // 262144 pixels

// ---- tile geometry ----
#define TX 256                 // pixels per block (half an image row)
#define LROW 272               // per-channel LDS row pitch in floats (TX+16)
#define LDS_F (5 * LROW)       // 1360 floats per channel plane
#define PAIR_F (2 * LDS_F)     // 2720 floats per interleaved channel-PAIR buffer
#define NGRP (5 * 68)          // 340 float4-groups per channel stage
#define CTR_IDX (2 * LROW + 4) // per-channel lds float idx of center tap minus t
#define NPAIR 16               // 16 channel pairs = 32 channels
#define WREG 1020              // float stride of wave-private guide region

// ============ Fused v12: v6 structure + channel-PAIR b64 reads ============
// 13-round model: total = phase0_burst + loop. v6's macro-structure
// (1024 blocks, phase-0 once per pixel, 32-channel loop) is optimal; the
// remaining lever is the loop's dominant cost: ~18.6us device-wide of
// ds_read_b32 tap reads. Fix: stage TWO channels element-interleaved in
// one buffer; each tap becomes ONE ds_read_b64 serving both channels
// (lane stride 8B -> 2 lanes/bank = conflict-free). LDS-read instruction
// count and barrier count both HALVE (16 pair-iterations).
// Writes become 2 x b128 at 32B lane stride (~2x cost, minor vs reads).
// Phase-0: v11's wave-private two-pass guide staging (fits sbuf union,
// LDS total 32.64 KB). (256,4) bound -> VGPR cap 128 (R10 spill lesson).
// FMA order per channel unchanged -> bitwise-identical output.
__global__ __launch_bounds__(256, 4) void adaptive_fused_v12(
    const float* __restrict__ depth,      // [B,1,H,W]
    const float* __restrict__ features,   // [B,C,H,W]
    const float* __restrict__ guide,      // [B,H,W,25]
    const int*   __restrict__ sample_idx, // [15]
    float*       __restrict__ out)        // [B,C,H,W] ++ [B,C,H,W] copy
{
    __shared__ float lds_raw[3 * PAIR_F];       // 8160 floats = 32.64 KB
    float (*sbuf)[PAIR_F] = reinterpret_cast<float (*)[PAIR_F]>(lds_raw);

    const int t    = threadIdx.x;
    const int lane = t & 63;
    const int wv   = t >> 6;

    // bijective XCD swizzle: 1024 blocks = 8 XCDs x 128 -> each XCD owns
    // 64 consecutive image rows (halo rows L2-local).
    const int orig = blockIdx.x;
    const int lid  = (orig & 7) * 128 + (orig >> 3);
    const int tile = lid & 1;
    const int y    = (lid >> 1) & (H_DIM - 1);
    const int b    = lid >> 9;
    const int x0   = tile * TX;
    const int x    = x0 + t;                    // this thread's pixel

    int sidx[S_NUM];
#pragma unroll
    for (int s = 0; s < S_NUM; ++s) sidx[s] = sample_idx[s];   // uniform

    // ---- staging addresses (constant across channels; v6-proven) ----
    // group g covers per-channel float positions [4g, 4g+4) of the 5x272
    // tile; image row y+g/68-2 clamp [0,H-1]; col x0-4+4*(g%68) clamp
    // [0,W-4]. Clamped dups are consumed only by weight-0 taps.
    int soff0, soff1 = 0;
    {
        const int g   = t;
        const int row = g / 68;
        const int col = (g - row * 68) * 4;
        int ir = y + row - 2; ir = ir < 0 ? 0 : (ir > H_DIM - 1 ? H_DIM - 1 : ir);
        int ic = x0 - 4 + col; ic = ic < 0 ? 0 : (ic > W_DIM - 4 ? W_DIM - 4 : ic);
        soff0 = ir * W_DIM + ic;
    }
    const bool has2 = (t < NGRP - 256);          // threads 0..83 stage group 2
    if (has2) {
        const int g   = 256 + t;
        const int row = g / 68;
        const int col = (g - row * 68) * 4;
        int ir = y + row - 2; ir = ir < 0 ? 0 : (ir > H_DIM - 1 ? H_DIM - 1 : ir);
        int ic = x0 - 4 + col; ic = ic < 0 ? 0 : (ic > W_DIM - 4 ? W_DIM - 4 : ic);
        soff1 = ir * W_DIM + ic;
    }

    const size_t hw  = (size_t)HW;
    const float* fpl = features + (size_t)b * C_DIM * hw;   // all 32 channels

    // ---- cross-phase prefetch: pair0 (ch0,ch1) + pair1 (ch2,ch3) issue
    //      NOW; phase 0 (guide passes, depth taps, exp) hides the latency --
    float4 aA0, aB0, aA1, aB1;      // pair 0
    float4 rA0, rB0, rA1, rB1;      // pair 1 (next to write)
    aA0 = *(const float4*)(fpl + soff0);
    aB0 = *(const float4*)(fpl + hw + soff0);
    if (has2) {
        aA1 = *(const float4*)(fpl + soff1);
        aB1 = *(const float4*)(fpl + hw + soff1);
    }
    {
        const float* f2 = fpl + 2 * hw;
        rA0 = *(const float4*)(f2 + soff0);
        rB0 = *(const float4*)(f2 + hw + soff0);
        if (has2) {
            rA1 = *(const float4*)(f2 + soff1);
            rB1 = *(const float4*)(f2 + hw + soff1);
        }
    }

    // ------------- phase 0: per-pixel weights (wave-private) -------------
    float posw[S_NUM];
    float psum = 0.f;
#pragma unroll
    for (int s = 0; s < S_NUM; ++s) {
        const float px = (float)(sidx[s] % K_SIZE);
        const float py = (float)(sidx[s] / K_SIZE);
        const float ddx = px - (float)(K_SIZE / 2);
        const float ddy = py - (float)(K_SIZE / 2);
        posw[s] = expf(-0.5f * sqrtf(ddx * ddx + ddy * ddy));
        psum += posw[s];
    }
    const float inv_psum = 1.f / psum;

    // pv[s] = v(depth@tap) * normalized posw (same multiply order as ever)
    float pv[S_NUM];
    unsigned inbm = 0;
    const int dbase = b * HW;
#pragma unroll
    for (int s = 0; s < S_NUM; ++s) {
        const int dy = sidx[s] / K_SIZE - PAD;
        const int dx = sidx[s] % K_SIZE - PAD;
        const int yy = y + dy;
        const int xx = x + dx;
        const bool inb = (yy >= 0) & (yy < H_DIM) & (xx >= 0) & (xx < W_DIM);
        float v = 0.f;
        if (inb) {
            const float d = depth[dbase + yy * W_DIM + xx];  // coalesced
            v = (d > 0.f && d < DEPTH_MAX) ? 1.f : 0.f;
        }
        pv[s] = v * (posw[s] * inv_psum);
        inbm |= (unsigned)inb << s;
    }

    // guide: wave-private staging in TWO 800-float passes (v11-proven);
    // raw[s] = pv[s] * guide_row[sidx[s]]  (order (v*poswn)*g, unchanged)
    float raw[S_NUM];
    {
        float* wreg = &lds_raw[wv * WREG];      // wave-private region
        const float* gbase =
            guide + (size_t)(b * HW + y * W_DIM + x0 + wv * 64) * G_NUM;
        {
            const float4* gsrc = (const float4*)gbase;
            float4* gdst = (float4*)wreg;
#pragma unroll
            for (int k = 0; k < 4; ++k) {
                const int idx = k * 64 + lane;
                if (idx < 200) gdst[idx] = gsrc[idx];
            }
        }
        __builtin_amdgcn_wave_barrier();
        if (lane < 32) {
            const float* gr = &wreg[lane * G_NUM];   // stride 25: conflict-free
#pragma unroll
            for (int s = 0; s < S_NUM; ++s) raw[s] = pv[s] * gr[sidx[s]];
        }
        __builtin_amdgcn_wave_barrier();
        {
            const float4* gsrc = (const float4*)(gbase + 32 * G_NUM);
            float4* gdst = (float4*)wreg;
#pragma unroll
            for (int k = 0; k < 4; ++k) {
                const int idx = k * 64 + lane;
                if (idx < 200) gdst[idx] = gsrc[idx];
            }
        }
        __builtin_amdgcn_wave_barrier();
        if (lane >= 32) {
            const float* gr = &wreg[(lane - 32) * G_NUM];
#pragma unroll
            for (int s = 0; s < S_NUM; ++s) raw[s] = pv[s] * gr[sidx[s]];
        }
    }

    // softmax over the 15 samples (matches jax.nn.softmax exactly)
    float mx = raw[0];
#pragma unroll
    for (int s = 1; s < S_NUM; ++s) mx = fmaxf(mx, raw[s]);
    float esum = 0.f;
    float wgt[S_NUM];
#pragma unroll
    for (int s = 0; s < S_NUM; ++s) {
        wgt[s] = expf(raw[s] - mx);
        esum += wgt[s];
    }
    const float inv_esum = 1.f / esum;
#pragma unroll
    for (int s = 0; s < S_NUM; ++s)
        wgt[s] = wgt[s] * inv_esum * (((inbm >> s) & 1u) ? 1.f : 0.f);

    // per-channel tap offsets (col = t + (si%5) + 2, always in range)
    int ldsoff[S_NUM];
#pragma unroll
    for (int s = 0; s < S_NUM; ++s) {
        const int si = sidx[s];
        ldsoff[s] = (si / K_SIZE) * LROW + t + (si % K_SIZE) + 2;
    }

    __syncthreads();                  // ALL waves done with guide regions

    // stage pair 0 into buf0, element-interleaved: position p -> {2p, 2p+1}
    {
        float* dst = sbuf[0];
        float4 w0, w1;
        w0.x = aA0.x; w0.y = aB0.x; w0.z = aA0.y; w0.w = aB0.y;
        w1.x = aA0.z; w1.y = aB0.z; w1.z = aA0.w; w1.w = aB0.w;
        *(float4*)&dst[8 * t]     = w0;
        *(float4*)&dst[8 * t + 4] = w1;
        if (has2) {
            w0.x = aA1.x; w0.y = aB1.x; w0.z = aA1.y; w0.w = aB1.y;
            w1.x = aA1.z; w1.y = aB1.z; w1.z = aA1.w; w1.w = aB1.w;
            *(float4*)&dst[8 * (256 + t)]     = w0;
            *(float4*)&dst[8 * (256 + t) + 4] = w1;
        }
    }
    __syncthreads();                  // pair0 ready

    float* o0 = out + (size_t)b * C_DIM * hw + (size_t)y * W_DIM + x0 + t;
    float* o1 = o0 + (size_t)B_DIM * C_DIM * hw;

    // ---- main loop over 16 channel pairs:
    //      write(pair p+1) | issue load(pair p+2) | compute(pair p) ----
#pragma unroll
    for (int p = 0; p < NPAIR; ++p) {
        if (p + 1 < NPAIR) {                      // compile-time (full unroll)
            float* dst = sbuf[(p + 1) % 3];
            float4 w0, w1;
            w0.x = rA0.x; w0.y = rB0.x; w0.z = rA0.y; w0.w = rB0.y;
            w1.x = rA0.z; w1.y = rB0.z; w1.z = rA0.w; w1.w = rB0.w;
            *(float4*)&dst[8 * t]     = w0;
            *(float4*)&dst[8 * t + 4] = w1;
            if (has2) {
                w0.x = rA1.x; w0.y = rB1.x; w0.z = rA1.y; w0.w = rB1.y;
                w1.x = rA1.z; w1.y = rB1.z; w1.z = rA1.w; w1.w = rB1.w;
                *(float4*)&dst[8 * (256 + t)]     = w0;
                *(float4*)&dst[8 * (256 + t) + 4] = w1;
            }
        }
        float4 nA0, nB0, nA1, nB1;
        if (p + 2 < NPAIR) {
            const float* fn = fpl + (size_t)(2 * (p + 2)) * hw;
            nA0 = *(const float4*)(fn + soff0);
            nB0 = *(const float4*)(fn + hw + soff0);
            if (has2) {
                nA1 = *(const float4*)(fn + soff1);
                nB1 = *(const float4*)(fn + hw + soff1);
            }
        }

        // compute pair p: 15 ds_read_b64 taps (both channels per read)
        const float* src = sbuf[p % 3];
        float accA = 0.f, accB = 0.f;
#pragma unroll
        for (int s = 0; s < S_NUM; ++s) {
            const float2 v = *(const float2*)&src[2 * ldsoff[s]];
            accA = fmaf(v.x, wgt[s], accA);
            accB = fmaf(v.y, wgt[s], accB);
        }
        const float2 ctr = *(const float2*)&src[2 * (CTR_IDX + t)];

        o0[(size_t)(2 * p) * hw]     = accA;      // coalesced stores
        o0[(size_t)(2 * p + 1) * hw] = accB;
        o1[(size_t)(2 * p) * hw]     = ctr.x;
        o1[(size_t)(2 * p + 1) * hw] = ctr.y;

        if (p + 2 < NPAIR) {
            rA0 = nA0; rB0 = nB0;
            if (has2) { rA1 = nA1; rB1 = nB1; }
        }
        __syncthreads();                          // sbuf[(p+1)%3] ready
    }
}

extern "C" void kernel_launch(void* const* d_in, const int* in_sizes, int n_in,
                              void* d_out, int out_size, void* d_ws, size_t ws_size,
                              hipStream_t stream) {
    const float* depth      = (const float*)d_in[0];
    const float* features   = (const float*)d_in[1];
    const float* guide      = (const float*)d_in[2];
    const int*   sample_idx = (const int*)d_in[3];

    float* out = (float*)d_out;
    const int blocks = NPX / TX;  // 1024

    adaptive_fused_v12<<<blocks, 256, 0, stream>>>(depth, features, guide,
                                                   sample_idx, out);
}

// Round 15
// 133.733 us; speedup vs baseline: 1.1211x; 1.0178x over previous
//
#include <hip/hip_runtime.h>
#include <math.h>

#define K_SIZE 5
#define PAD 2
#define DEPTH_MAX 192.0f
#define S_NUM 15
#define G_NUM (K_SIZE * K_SIZE)   // 25

// Fixed problem shape (from reference setup_inputs):
#define B_DIM 2
#define C_DIM 32
#define H_DIM 256
#define W_DIM 512
#define HW (H_DIM * W_DIM)
#define NPX (B_DIM * HW)              // 262144 pixels

// ---- tile geometry ----
#define TX 128                 // pixels per block (quarter image row)
#define LROW 144               // per-channel LDS row pitch (TX+16)
#define CPLANE (5 * LROW)      // 720 floats per channel plane
#define PAIR_F (2 * CPLANE)    // 1440 floats per interleaved channel-PAIR buffer
#define NGRP (5 * 36)          // 180 float4-groups per channel stage
#define NPAIR 16               // 16 channel pairs = 32 channels
#define CTR_IDX (2 * LROW + 4) // per-channel lds idx of center tap minus t

// ========= Fused v13: v12 pair-b64 loop at TX=128 + 1-pass phase-0 ========
// v12 (44.2us) wins analysis: loop cost halved by pair reads; remaining
// cost is latency/convoy exposure. v13 attacks that:
//  - TX=128: 2048 blocks x 2 waves (same 16 waves/CU structural cap of
//    fused-phase-0, but 8 blocks/CU: finer tail, 2-wave barriers, LDS
//    17.28 KB/block)
//  - phase-0 guide staging in ONE wave-private pass (v12's two-pass was a
//    16KB-era relic; all 64 lanes read, one exposed-latency phase fewer)
// Everything else proven: pair-interleaved b64 taps (conflict-free reads),
// triple-buffer 2-deep prefetch, bijective XCD swizzle, multiply order
// unchanged -> bitwise-identical output.
__global__ __launch_bounds__(128, 4) void adaptive_fused_v13(
    const float* __restrict__ depth,      // [B,1,H,W]
    const float* __restrict__ features,   // [B,C,H,W]
    const float* __restrict__ guide,      // [B,H,W,25]
    const int*   __restrict__ sample_idx, // [15]
    float*       __restrict__ out)        // [B,C,H,W] ++ [B,C,H,W] copy
{
    __shared__ float lds_raw[3 * PAIR_F];       // 4320 floats = 17.28 KB
    float (*sbuf)[PAIR_F] = reinterpret_cast<float (*)[PAIR_F]>(lds_raw);

    const int t    = threadIdx.x;               // 0..127
    const int lane = t & 63;
    const int wv   = t >> 6;                    // 0 or 1

    // bijective XCD swizzle: 2048 blocks = 8 XCDs x 256 -> each XCD owns
    // 64 consecutive image rows (halo rows L2-local).
    const int orig = blockIdx.x;
    const int lid  = (orig & 7) * 256 + (orig >> 3);
    const int tile = lid & 3;                   // 4 x-tiles per row
    const int y    = (lid >> 2) & (H_DIM - 1);
    const int b    = lid >> 10;
    const int x0   = tile * TX;
    const int x    = x0 + t;                    // this thread's pixel

    int sidx[S_NUM];
#pragma unroll
    for (int s = 0; s < S_NUM; ++s) sidx[s] = sample_idx[s];   // uniform

    // ---- staging addresses (constant across channels) ----
    // group g: lds row g/36, col 4*(g%36); image row y+g/36-2 clamp
    // [0,H-1]; image col x0-4+4*(g%36) clamp [0,W-4]. Clamped dups are
    // consumed only by weight-0 taps (exactness arg unchanged).
    int soff0, soff1 = 0;
    {
        const int row = t / 36;
        const int col = (t - row * 36) * 4;
        int ir = y + row - 2; ir = ir < 0 ? 0 : (ir > H_DIM - 1 ? H_DIM - 1 : ir);
        int ic = x0 - 4 + col; ic = ic < 0 ? 0 : (ic > W_DIM - 4 ? W_DIM - 4 : ic);
        soff0 = ir * W_DIM + ic;
    }
    const bool has2 = (t < NGRP - 128);          // threads 0..51: group 128+t
    if (has2) {
        const int g   = 128 + t;
        const int row = g / 36;
        const int col = (g - row * 36) * 4;
        int ir = y + row - 2; ir = ir < 0 ? 0 : (ir > H_DIM - 1 ? H_DIM - 1 : ir);
        int ic = x0 - 4 + col; ic = ic < 0 ? 0 : (ic > W_DIM - 4 ? W_DIM - 4 : ic);
        soff1 = ir * W_DIM + ic;
    }

    const size_t hw  = (size_t)HW;
    const float* fpl = features + (size_t)b * C_DIM * hw;   // all 32 channels

    // ---- cross-phase prefetch: pair0 (ch0,ch1) + pair1 (ch2,ch3) issue
    //      NOW; phase 0 (guide pass, depth taps, exp) hides the latency ----
    float4 aA0, aB0, aA1, aB1;      // pair 0
    float4 rA0, rB0, rA1, rB1;      // pair 1 (next to write)
    aA0 = *(const float4*)(fpl + soff0);
    aB0 = *(const float4*)(fpl + hw + soff0);
    if (has2) {
        aA1 = *(const float4*)(fpl + soff1);
        aB1 = *(const float4*)(fpl + hw + soff1);
    }
    {
        const float* f2 = fpl + 2 * hw;
        rA0 = *(const float4*)(f2 + soff0);
        rB0 = *(const float4*)(f2 + hw + soff0);
        if (has2) {
            rA1 = *(const float4*)(f2 + soff1);
            rB1 = *(const float4*)(f2 + hw + soff1);
        }
    }

    // ------------- phase 0: per-pixel weights (wave-private) -------------
    float posw[S_NUM];
    float psum = 0.f;
#pragma unroll
    for (int s = 0; s < S_NUM; ++s) {
        const float px = (float)(sidx[s] % K_SIZE);
        const float py = (float)(sidx[s] / K_SIZE);
        const float ddx = px - (float)(K_SIZE / 2);
        const float ddy = py - (float)(K_SIZE / 2);
        posw[s] = expf(-0.5f * sqrtf(ddx * ddx + ddy * ddy));
        psum += posw[s];
    }
    const float inv_psum = 1.f / psum;

    // pv[s] = v(depth@tap) * normalized posw (same multiply order as ever)
    float pv[S_NUM];
    unsigned inbm = 0;
    const int dbase = b * HW;
#pragma unroll
    for (int s = 0; s < S_NUM; ++s) {
        const int dy = sidx[s] / K_SIZE - PAD;
        const int dx = sidx[s] % K_SIZE - PAD;
        const int yy = y + dy;
        const int xx = x + dx;
        const bool inb = (yy >= 0) & (yy < H_DIM) & (xx >= 0) & (xx < W_DIM);
        float v = 0.f;
        if (inb) {
            const float d = depth[dbase + yy * W_DIM + xx];  // coalesced
            v = (d > 0.f && d < DEPTH_MAX) ? 1.f : 0.f;
        }
        pv[s] = v * (posw[s] * inv_psum);
        inbm |= (unsigned)inb << s;
    }

    // guide: ONE wave-private pass — wave wv stages its 64 pixels' rows
    // (1600 floats = 400 float4) into its slice, all lanes then read.
    // raw[s] = pv[s] * guide_row[sidx[s]]  (order (v*poswn)*g, unchanged)
    float raw[S_NUM];
    {
        float* wreg = &lds_raw[wv * 1600];      // [0,3200) < 4320 floats
        const float* gbase =
            guide + (size_t)(b * HW + y * W_DIM + x0 + wv * 64) * G_NUM;
        const float4* gsrc = (const float4*)gbase;
        float4* gdst = (float4*)wreg;
#pragma unroll
        for (int k = 0; k < 7; ++k) {
            const int idx = k * 64 + lane;
            if (idx < 400) gdst[idx] = gsrc[idx];   // coalesced
        }
        __builtin_amdgcn_wave_barrier();
        const float* gr = &wreg[lane * G_NUM];      // stride 25: conflict-free
#pragma unroll
        for (int s = 0; s < S_NUM; ++s) raw[s] = pv[s] * gr[sidx[s]];
    }

    // softmax over the 15 samples (matches jax.nn.softmax exactly)
    float mx = raw[0];
#pragma unroll
    for (int s = 1; s < S_NUM; ++s) mx = fmaxf(mx, raw[s]);
    float esum = 0.f;
    float wgt[S_NUM];
#pragma unroll
    for (int s = 0; s < S_NUM; ++s) {
        wgt[s] = expf(raw[s] - mx);
        esum += wgt[s];
    }
    const float inv_esum = 1.f / esum;
#pragma unroll
    for (int s = 0; s < S_NUM; ++s)
        wgt[s] = wgt[s] * inv_esum * (((inbm >> s) & 1u) ? 1.f : 0.f);

    // per-channel tap offsets (col = t + (si%5) + 2 <= 133 < 144)
    int ldsoff[S_NUM];
#pragma unroll
    for (int s = 0; s < S_NUM; ++s) {
        const int si = sidx[s];
        ldsoff[s] = (si / K_SIZE) * LROW + t + (si % K_SIZE) + 2;
    }

    __syncthreads();                  // ALL waves done with guide regions

    // stage pair 0 into buf0, element-interleaved: position p -> {2p,2p+1}
    {
        float* dst = sbuf[0];
        float4 w0, w1;
        w0.x = aA0.x; w0.y = aB0.x; w0.z = aA0.y; w0.w = aB0.y;
        w1.x = aA0.z; w1.y = aB0.z; w1.z = aA0.w; w1.w = aB0.w;
        *(float4*)&dst[8 * t]     = w0;
        *(float4*)&dst[8 * t + 4] = w1;
        if (has2) {
            w0.x = aA1.x; w0.y = aB1.x; w0.z = aA1.y; w0.w = aB1.y;
            w1.x = aA1.z; w1.y = aB1.z; w1.z = aA1.w; w1.w = aB1.w;
            *(float4*)&dst[8 * (128 + t)]     = w0;
            *(float4*)&dst[8 * (128 + t) + 4] = w1;
        }
    }
    __syncthreads();                  // pair0 ready

    float* o0 = out + (size_t)b * C_DIM * hw + (size_t)y * W_DIM + x0 + t;
    float* o1 = o0 + (size_t)B_DIM * C_DIM * hw;

    // ---- main loop over 16 channel pairs:
    //      write(pair p+1) | issue load(pair p+2) | compute(pair p) ----
#pragma unroll
    for (int p = 0; p < NPAIR; ++p) {
        if (p + 1 < NPAIR) {                      // compile-time (full unroll)
            float* dst = sbuf[(p + 1) % 3];
            float4 w0, w1;
            w0.x = rA0.x; w0.y = rB0.x; w0.z = rA0.y; w0.w = rB0.y;
            w1.x = rA0.z; w1.y = rB0.z; w1.z = rA0.w; w1.w = rB0.w;
            *(float4*)&dst[8 * t]     = w0;
            *(float4*)&dst[8 * t + 4] = w1;
            if (has2) {
                w0.x = rA1.x; w0.y = rB1.x; w0.z = rA1.y; w0.w = rB1.y;
                w1.x = rA1.z; w1.y = rB1.z; w1.z = rA1.w; w1.w = rB1.w;
                *(float4*)&dst[8 * (128 + t)]     = w0;
                *(float4*)&dst[8 * (128 + t) + 4] = w1;
            }
        }
        float4 nA0, nB0, nA1, nB1;
        if (p + 2 < NPAIR) {
            const float* fn = fpl + (size_t)(2 * (p + 2)) * hw;
            nA0 = *(const float4*)(fn + soff0);
            nB0 = *(const float4*)(fn + hw + soff0);
            if (has2) {
                nA1 = *(const float4*)(fn + soff1);
                nB1 = *(const float4*)(fn + hw + soff1);
            }
        }

        // compute pair p: 15 ds_read_b64 taps (both channels per read)
        const float* src = sbuf[p % 3];
        float accA = 0.f, accB = 0.f;
#pragma unroll
        for (int s = 0; s < S_NUM; ++s) {
            const float2 v = *(const float2*)&src[2 * ldsoff[s]];
            accA = fmaf(v.x, wgt[s], accA);
            accB = fmaf(v.y, wgt[s], accB);
        }
        const float2 ctr = *(const float2*)&src[2 * (CTR_IDX + t)];

        o0[(size_t)(2 * p) * hw]     = accA;      // coalesced stores
        o0[(size_t)(2 * p + 1) * hw] = accB;
        o1[(size_t)(2 * p) * hw]     = ctr.x;
        o1[(size_t)(2 * p + 1) * hw] = ctr.y;

        if (p + 2 < NPAIR) {
            rA0 = nA0; rB0 = nB0;
            if (has2) { rA1 = nA1; rB1 = nB1; }
        }
        __syncthreads();                          // sbuf[(p+1)%3] ready
    }
}

extern "C" void kernel_launch(void* const* d_in, const int* in_sizes, int n_in,
                              void* d_out, int out_size, void* d_ws, size_t ws_size,
                              hipStream_t stream) {
    const float* depth      = (const float*)d_in[0];
    const float* features   = (const float*)d_in[1];
    const float* guide      = (const float*)d_in[2];
    const int*   sample_idx = (const int*)d_in[3];

    float* out = (float*)d_out;
    const int blocks = NPX / TX;  // 2048

    adaptive_fused_v13<<<blocks, 128, 0, stream>>>(depth, features, guide,
                                                   sample_idx, out);
}

// Round 16
// 132.882 us; speedup vs baseline: 1.1283x; 1.0064x over previous
//
#include <hip/hip_runtime.h>
#include <math.h>

#define K_SIZE 5
#define PAD 2
#define DEPTH_MAX 192.0f
#define S_NUM 15
#define G_NUM (K_SIZE * K_SIZE)   // 25

// Fixed problem shape (from reference setup_inputs):
#define B_DIM 2
#define C_DIM 32
#define H_DIM 256
#define W_DIM 512
#define HW (H_DIM * W_DIM)
#define NPX (B_DIM * HW)              // 262144 pixels

// ---- tile geometry (v12-proven) ----
#define TX 256                 // pixels per block (half an image row)
#define LROW 272               // per-channel LDS row pitch in floats (TX+16)
#define LDS_F (5 * LROW)       // 1360 floats per channel plane
#define PAIR_F (2 * LDS_F)     // 2720 floats per interleaved channel-PAIR buffer
#define NGRP (5 * 68)          // 340 float4-groups per channel stage
#define CTR_IDX (2 * LROW + 4) // per-channel lds float idx of center tap minus t
#define NPAIR 16               // 16 channel pairs = 32 channels
#define GFL4 1600              // guide slice: 6400 floats = 1600 float4 = 25.6 KB

// ========== Fused v14: v12 loop + ONE-PASS block-wide phase-0 =============
// v12 (44.2us kernel, best) still used the two-pass wave-private guide
// staging designed for a 16.3 KB region. The pair-buffer union is 32.64 KB,
// so the whole block's guide slice (25.6 KB) fits in ONE cooperative pass:
// all 256 threads stage 1600 float4 coalesced, one sync, every thread
// reads its stride-25 row conflict-free. Removes two half-idle read
// passes, two fences, and one exposed global-load burst.
// Loop unchanged from v12: pair-interleaved b64 taps (conflict-free),
// triple-buffer 2-deep prefetch, XCD swizzle, (256,4) bounds.
// Multiply order unchanged -> bitwise-identical output.
__global__ __launch_bounds__(256, 4) void adaptive_fused_v14(
    const float* __restrict__ depth,      // [B,1,H,W]
    const float* __restrict__ features,   // [B,C,H,W]
    const float* __restrict__ guide,      // [B,H,W,25]
    const int*   __restrict__ sample_idx, // [15]
    float*       __restrict__ out)        // [B,C,H,W] ++ [B,C,H,W] copy
{
    __shared__ float lds_raw[3 * PAIR_F];       // 8160 floats = 32.64 KB
    float (*sbuf)[PAIR_F] = reinterpret_cast<float (*)[PAIR_F]>(lds_raw);

    const int t = threadIdx.x;

    // bijective XCD swizzle: 1024 blocks = 8 XCDs x 128 -> each XCD owns
    // 64 consecutive image rows (halo rows L2-local).
    const int orig = blockIdx.x;
    const int lid  = (orig & 7) * 128 + (orig >> 3);
    const int tile = lid & 1;
    const int y    = (lid >> 1) & (H_DIM - 1);
    const int b    = lid >> 9;
    const int x0   = tile * TX;
    const int x    = x0 + t;                    // this thread's pixel

    int sidx[S_NUM];
#pragma unroll
    for (int s = 0; s < S_NUM; ++s) sidx[s] = sample_idx[s];   // uniform

    // ---- staging addresses (constant across channels; v6-proven) ----
    int soff0, soff1 = 0;
    {
        const int g   = t;
        const int row = g / 68;
        const int col = (g - row * 68) * 4;
        int ir = y + row - 2; ir = ir < 0 ? 0 : (ir > H_DIM - 1 ? H_DIM - 1 : ir);
        int ic = x0 - 4 + col; ic = ic < 0 ? 0 : (ic > W_DIM - 4 ? W_DIM - 4 : ic);
        soff0 = ir * W_DIM + ic;
    }
    const bool has2 = (t < NGRP - 256);          // threads 0..83 stage group 2
    if (has2) {
        const int g   = 256 + t;
        const int row = g / 68;
        const int col = (g - row * 68) * 4;
        int ir = y + row - 2; ir = ir < 0 ? 0 : (ir > H_DIM - 1 ? H_DIM - 1 : ir);
        int ic = x0 - 4 + col; ic = ic < 0 ? 0 : (ic > W_DIM - 4 ? W_DIM - 4 : ic);
        soff1 = ir * W_DIM + ic;
    }

    const size_t hw  = (size_t)HW;
    const float* fpl = features + (size_t)b * C_DIM * hw;   // all 32 channels

    // ---- cross-phase prefetch: pair0 (ch0,ch1) + pair1 (ch2,ch3) issue
    //      NOW; phase 0 (guide pass, depth taps, exp) hides the latency ----
    float4 aA0, aB0, aA1, aB1;      // pair 0
    float4 rA0, rB0, rA1, rB1;      // pair 1 (next to write)
    aA0 = *(const float4*)(fpl + soff0);
    aB0 = *(const float4*)(fpl + hw + soff0);
    if (has2) {
        aA1 = *(const float4*)(fpl + soff1);
        aB1 = *(const float4*)(fpl + hw + soff1);
    }
    {
        const float* f2 = fpl + 2 * hw;
        rA0 = *(const float4*)(f2 + soff0);
        rB0 = *(const float4*)(f2 + hw + soff0);
        if (has2) {
            rA1 = *(const float4*)(f2 + soff1);
            rB1 = *(const float4*)(f2 + hw + soff1);
        }
    }

    // ------------- phase 0: per-pixel weights -----------------------------
    float posw[S_NUM];
    float psum = 0.f;
#pragma unroll
    for (int s = 0; s < S_NUM; ++s) {
        const float px = (float)(sidx[s] % K_SIZE);
        const float py = (float)(sidx[s] / K_SIZE);
        const float ddx = px - (float)(K_SIZE / 2);
        const float ddy = py - (float)(K_SIZE / 2);
        posw[s] = expf(-0.5f * sqrtf(ddx * ddx + ddy * ddy));
        psum += posw[s];
    }
    const float inv_psum = 1.f / psum;

    // pv[s] = v(depth@tap) * normalized posw (same multiply order as ever)
    float pv[S_NUM];
    unsigned inbm = 0;
    const int dbase = b * HW;
#pragma unroll
    for (int s = 0; s < S_NUM; ++s) {
        const int dy = sidx[s] / K_SIZE - PAD;
        const int dx = sidx[s] % K_SIZE - PAD;
        const int yy = y + dy;
        const int xx = x + dx;
        const bool inb = (yy >= 0) & (yy < H_DIM) & (xx >= 0) & (xx < W_DIM);
        float v = 0.f;
        if (inb) {
            const float d = depth[dbase + yy * W_DIM + xx];  // coalesced
            v = (d > 0.f && d < DEPTH_MAX) ? 1.f : 0.f;
        }
        pv[s] = v * (posw[s] * inv_psum);
        inbm |= (unsigned)inb << s;
    }

    // guide: ONE cooperative block-wide pass (6400 floats = 1600 float4,
    // fully coalesced; fits the 32.64 KB union). Then every thread reads
    // its stride-25 row conflict-free.
    // raw[s] = pv[s] * guide_row[sidx[s]]  (order (v*poswn)*g, unchanged)
    float raw[S_NUM];
    {
        const float4* gsrc =
            (const float4*)(guide + (size_t)(b * HW + y * W_DIM + x0) * G_NUM);
        float4* gdst = (float4*)lds_raw;
#pragma unroll
        for (int k = 0; k < 7; ++k) {
            const int idx = k * 256 + t;
            if (idx < GFL4) gdst[idx] = gsrc[idx];
        }
        __syncthreads();
        const float* gr = &lds_raw[t * G_NUM];      // stride 25: conflict-free
#pragma unroll
        for (int s = 0; s < S_NUM; ++s) raw[s] = pv[s] * gr[sidx[s]];
    }

    // softmax over the 15 samples (matches jax.nn.softmax exactly)
    float mx = raw[0];
#pragma unroll
    for (int s = 1; s < S_NUM; ++s) mx = fmaxf(mx, raw[s]);
    float esum = 0.f;
    float wgt[S_NUM];
#pragma unroll
    for (int s = 0; s < S_NUM; ++s) {
        wgt[s] = expf(raw[s] - mx);
        esum += wgt[s];
    }
    const float inv_esum = 1.f / esum;
#pragma unroll
    for (int s = 0; s < S_NUM; ++s)
        wgt[s] = wgt[s] * inv_esum * (((inbm >> s) & 1u) ? 1.f : 0.f);

    // per-channel tap offsets (col = t + (si%5) + 2, always in range)
    int ldsoff[S_NUM];
#pragma unroll
    for (int s = 0; s < S_NUM; ++s) {
        const int si = sidx[s];
        ldsoff[s] = (si / K_SIZE) * LROW + t + (si % K_SIZE) + 2;
    }

    __syncthreads();                  // all guide reads done -> reuse safe

    // stage pair 0 into buf0, element-interleaved: position p -> {2p, 2p+1}
    {
        float* dst = sbuf[0];
        float4 w0, w1;
        w0.x = aA0.x; w0.y = aB0.x; w0.z = aA0.y; w0.w = aB0.y;
        w1.x = aA0.z; w1.y = aB0.z; w1.z = aA0.w; w1.w = aB0.w;
        *(float4*)&dst[8 * t]     = w0;
        *(float4*)&dst[8 * t + 4] = w1;
        if (has2) {
            w0.x = aA1.x; w0.y = aB1.x; w0.z = aA1.y; w0.w = aB1.y;
            w1.x = aA1.z; w1.y = aB1.z; w1.z = aA1.w; w1.w = aB1.w;
            *(float4*)&dst[8 * (256 + t)]     = w0;
            *(float4*)&dst[8 * (256 + t) + 4] = w1;
        }
    }
    __syncthreads();                  // pair0 ready

    float* o0 = out + (size_t)b * C_DIM * hw + (size_t)y * W_DIM + x0 + t;
    float* o1 = o0 + (size_t)B_DIM * C_DIM * hw;

    // ---- main loop over 16 channel pairs (v12-proven):
    //      write(pair p+1) | issue load(pair p+2) | compute(pair p) ----
#pragma unroll
    for (int p = 0; p < NPAIR; ++p) {
        if (p + 1 < NPAIR) {                      // compile-time (full unroll)
            float* dst = sbuf[(p + 1) % 3];
            float4 w0, w1;
            w0.x = rA0.x; w0.y = rB0.x; w0.z = rA0.y; w0.w = rB0.y;
            w1.x = rA0.z; w1.y = rB0.z; w1.z = rA0.w; w1.w = rB0.w;
            *(float4*)&dst[8 * t]     = w0;
            *(float4*)&dst[8 * t + 4] = w1;
            if (has2) {
                w0.x = rA1.x; w0.y = rB1.x; w0.z = rA1.y; w0.w = rB1.y;
                w1.x = rA1.z; w1.y = rB1.z; w1.z = rA1.w; w1.w = rB1.w;
                *(float4*)&dst[8 * (256 + t)]     = w0;
                *(float4*)&dst[8 * (256 + t) + 4] = w1;
            }
        }
        float4 nA0, nB0, nA1, nB1;
        if (p + 2 < NPAIR) {
            const float* fn = fpl + (size_t)(2 * (p + 2)) * hw;
            nA0 = *(const float4*)(fn + soff0);
            nB0 = *(const float4*)(fn + hw + soff0);
            if (has2) {
                nA1 = *(const float4*)(fn + soff1);
                nB1 = *(const float4*)(fn + hw + soff1);
            }
        }

        // compute pair p: 15 ds_read_b64 taps (both channels per read)
        const float* src = sbuf[p % 3];
        float accA = 0.f, accB = 0.f;
#pragma unroll
        for (int s = 0; s < S_NUM; ++s) {
            const float2 v = *(const float2*)&src[2 * ldsoff[s]];
            accA = fmaf(v.x, wgt[s], accA);
            accB = fmaf(v.y, wgt[s], accB);
        }
        const float2 ctr = *(const float2*)&src[2 * (CTR_IDX + t)];

        o0[(size_t)(2 * p) * hw]     = accA;      // coalesced stores
        o0[(size_t)(2 * p + 1) * hw] = accB;
        o1[(size_t)(2 * p) * hw]     = ctr.x;
        o1[(size_t)(2 * p + 1) * hw] = ctr.y;

        if (p + 2 < NPAIR) {
            rA0 = nA0; rB0 = nB0;
            if (has2) { rA1 = nA1; rB1 = nB1; }
        }
        __syncthreads();                          // sbuf[(p+1)%3] ready
    }
}

extern "C" void kernel_launch(void* const* d_in, const int* in_sizes, int n_in,
                              void* d_out, int out_size, void* d_ws, size_t ws_size,
                              hipStream_t stream) {
    const float* depth      = (const float*)d_in[0];
    const float* features   = (const float*)d_in[1];
    const float* guide      = (const float*)d_in[2];
    const int*   sample_idx = (const int*)d_in[3];

    float* out = (float*)d_out;
    const int blocks = NPX / TX;  // 1024

    adaptive_fused_v14<<<blocks, 256, 0, stream>>>(depth, features, guide,
                                                   sample_idx, out);
}

// Round 17
// 132.399 us; speedup vs baseline: 1.1324x; 1.0036x over previous
//
#include <hip/hip_runtime.h>
#include <math.h>

#define K_SIZE 5
#define PAD 2
#define DEPTH_MAX 192.0f
#define S_NUM 15
#define G_NUM (K_SIZE * K_SIZE)   // 25

// Fixed problem shape (from reference setup_inputs):
#define B_DIM 2
#define C_DIM 32
#define H_DIM 256
#define W_DIM 512
#define HW (H_DIM * W_DIM)
#define NPX (B_DIM * HW)              // 262144 pixels

// ---- tile geometry ----
#define TX 256                 // pixels per block (half an image row)
#define LROW 272               // per-channel LDS row pitch in floats (TX+16)
#define LDS_F (5 * LROW)       // 1360 floats per channel plane
#define PAIR_F (2 * LDS_F)     // 2720 floats per interleaved channel-PAIR buffer
#define NGRP (5 * 68)          // 340 float4-groups per channel stage
#define CTR_IDX (2 * LROW + 4) // per-channel lds float idx of center tap minus t
#define NPAIR 16               // 16 channel pairs = 32 channels
#define WREG 1020              // float stride of wave-private guide region

// ===================== v12 EXACT REVERT (best kernel: 44.2 us) ============
// R16 lesson: v14's one-pass phase-0 perturbed the MAIN LOOP's codegen
// (VGPR 56->52, prefetch MLP lost, 44.2 -> 63.9us with identical traffic).
// v12's exact source is load-bearing — restored byte-for-byte.
// Structure: 1024 blocks (phase-0 once per pixel), pair-interleaved b64
// taps (LDS-read issue halved, conflict-free), triple-buffer 2-deep
// prefetch, two-pass wave-private guide staging, bijective XCD swizzle,
// (256,4) bounds. Multiply order matches reference -> bitwise-identical.
__global__ __launch_bounds__(256, 4) void adaptive_fused_v12(
    const float* __restrict__ depth,      // [B,1,H,W]
    const float* __restrict__ features,   // [B,C,H,W]
    const float* __restrict__ guide,      // [B,H,W,25]
    const int*   __restrict__ sample_idx, // [15]
    float*       __restrict__ out)        // [B,C,H,W] ++ [B,C,H,W] copy
{
    __shared__ float lds_raw[3 * PAIR_F];       // 8160 floats = 32.64 KB
    float (*sbuf)[PAIR_F] = reinterpret_cast<float (*)[PAIR_F]>(lds_raw);

    const int t    = threadIdx.x;
    const int lane = t & 63;
    const int wv   = t >> 6;

    // bijective XCD swizzle: 1024 blocks = 8 XCDs x 128 -> each XCD owns
    // 64 consecutive image rows (halo rows L2-local).
    const int orig = blockIdx.x;
    const int lid  = (orig & 7) * 128 + (orig >> 3);
    const int tile = lid & 1;
    const int y    = (lid >> 1) & (H_DIM - 1);
    const int b    = lid >> 9;
    const int x0   = tile * TX;
    const int x    = x0 + t;                    // this thread's pixel

    int sidx[S_NUM];
#pragma unroll
    for (int s = 0; s < S_NUM; ++s) sidx[s] = sample_idx[s];   // uniform

    // ---- staging addresses (constant across channels; v6-proven) ----
    // group g covers per-channel float positions [4g, 4g+4) of the 5x272
    // tile; image row y+g/68-2 clamp [0,H-1]; col x0-4+4*(g%68) clamp
    // [0,W-4]. Clamped dups are consumed only by weight-0 taps.
    int soff0, soff1 = 0;
    {
        const int g   = t;
        const int row = g / 68;
        const int col = (g - row * 68) * 4;
        int ir = y + row - 2; ir = ir < 0 ? 0 : (ir > H_DIM - 1 ? H_DIM - 1 : ir);
        int ic = x0 - 4 + col; ic = ic < 0 ? 0 : (ic > W_DIM - 4 ? W_DIM - 4 : ic);
        soff0 = ir * W_DIM + ic;
    }
    const bool has2 = (t < NGRP - 256);          // threads 0..83 stage group 2
    if (has2) {
        const int g   = 256 + t;
        const int row = g / 68;
        const int col = (g - row * 68) * 4;
        int ir = y + row - 2; ir = ir < 0 ? 0 : (ir > H_DIM - 1 ? H_DIM - 1 : ir);
        int ic = x0 - 4 + col; ic = ic < 0 ? 0 : (ic > W_DIM - 4 ? W_DIM - 4 : ic);
        soff1 = ir * W_DIM + ic;
    }

    const size_t hw  = (size_t)HW;
    const float* fpl = features + (size_t)b * C_DIM * hw;   // all 32 channels

    // ---- cross-phase prefetch: pair0 (ch0,ch1) + pair1 (ch2,ch3) issue
    //      NOW; phase 0 (guide passes, depth taps, exp) hides the latency --
    float4 aA0, aB0, aA1, aB1;      // pair 0
    float4 rA0, rB0, rA1, rB1;      // pair 1 (next to write)
    aA0 = *(const float4*)(fpl + soff0);
    aB0 = *(const float4*)(fpl + hw + soff0);
    if (has2) {
        aA1 = *(const float4*)(fpl + soff1);
        aB1 = *(const float4*)(fpl + hw + soff1);
    }
    {
        const float* f2 = fpl + 2 * hw;
        rA0 = *(const float4*)(f2 + soff0);
        rB0 = *(const float4*)(f2 + hw + soff0);
        if (has2) {
            rA1 = *(const float4*)(f2 + soff1);
            rB1 = *(const float4*)(f2 + hw + soff1);
        }
    }

    // ------------- phase 0: per-pixel weights (wave-private) -------------
    float posw[S_NUM];
    float psum = 0.f;
#pragma unroll
    for (int s = 0; s < S_NUM; ++s) {
        const float px = (float)(sidx[s] % K_SIZE);
        const float py = (float)(sidx[s] / K_SIZE);
        const float ddx = px - (float)(K_SIZE / 2);
        const float ddy = py - (float)(K_SIZE / 2);
        posw[s] = expf(-0.5f * sqrtf(ddx * ddx + ddy * ddy));
        psum += posw[s];
    }
    const float inv_psum = 1.f / psum;

    // pv[s] = v(depth@tap) * normalized posw (same multiply order as ever)
    float pv[S_NUM];
    unsigned inbm = 0;
    const int dbase = b * HW;
#pragma unroll
    for (int s = 0; s < S_NUM; ++s) {
        const int dy = sidx[s] / K_SIZE - PAD;
        const int dx = sidx[s] % K_SIZE - PAD;
        const int yy = y + dy;
        const int xx = x + dx;
        const bool inb = (yy >= 0) & (yy < H_DIM) & (xx >= 0) & (xx < W_DIM);
        float v = 0.f;
        if (inb) {
            const float d = depth[dbase + yy * W_DIM + xx];  // coalesced
            v = (d > 0.f && d < DEPTH_MAX) ? 1.f : 0.f;
        }
        pv[s] = v * (posw[s] * inv_psum);
        inbm |= (unsigned)inb << s;
    }

    // guide: wave-private staging in TWO 800-float passes (v11-proven);
    // raw[s] = pv[s] * guide_row[sidx[s]]  (order (v*poswn)*g, unchanged)
    float raw[S_NUM];
    {
        float* wreg = &lds_raw[wv * WREG];      // wave-private region
        const float* gbase =
            guide + (size_t)(b * HW + y * W_DIM + x0 + wv * 64) * G_NUM;
        {
            const float4* gsrc = (const float4*)gbase;
            float4* gdst = (float4*)wreg;
#pragma unroll
            for (int k = 0; k < 4; ++k) {
                const int idx = k * 64 + lane;
                if (idx < 200) gdst[idx] = gsrc[idx];
            }
        }
        __builtin_amdgcn_wave_barrier();
        if (lane < 32) {
            const float* gr = &wreg[lane * G_NUM];   // stride 25: conflict-free
#pragma unroll
            for (int s = 0; s < S_NUM; ++s) raw[s] = pv[s] * gr[sidx[s]];
        }
        __builtin_amdgcn_wave_barrier();
        {
            const float4* gsrc = (const float4*)(gbase + 32 * G_NUM);
            float4* gdst = (float4*)wreg;
#pragma unroll
            for (int k = 0; k < 4; ++k) {
                const int idx = k * 64 + lane;
                if (idx < 200) gdst[idx] = gsrc[idx];
            }
        }
        __builtin_amdgcn_wave_barrier();
        if (lane >= 32) {
            const float* gr = &wreg[(lane - 32) * G_NUM];
#pragma unroll
            for (int s = 0; s < S_NUM; ++s) raw[s] = pv[s] * gr[sidx[s]];
        }
    }

    // softmax over the 15 samples (matches jax.nn.softmax exactly)
    float mx = raw[0];
#pragma unroll
    for (int s = 1; s < S_NUM; ++s) mx = fmaxf(mx, raw[s]);
    float esum = 0.f;
    float wgt[S_NUM];
#pragma unroll
    for (int s = 0; s < S_NUM; ++s) {
        wgt[s] = expf(raw[s] - mx);
        esum += wgt[s];
    }
    const float inv_esum = 1.f / esum;
#pragma unroll
    for (int s = 0; s < S_NUM; ++s)
        wgt[s] = wgt[s] * inv_esum * (((inbm >> s) & 1u) ? 1.f : 0.f);

    // per-channel tap offsets (col = t + (si%5) + 2, always in range)
    int ldsoff[S_NUM];
#pragma unroll
    for (int s = 0; s < S_NUM; ++s) {
        const int si = sidx[s];
        ldsoff[s] = (si / K_SIZE) * LROW + t + (si % K_SIZE) + 2;
    }

    __syncthreads();                  // ALL waves done with guide regions

    // stage pair 0 into buf0, element-interleaved: position p -> {2p, 2p+1}
    {
        float* dst = sbuf[0];
        float4 w0, w1;
        w0.x = aA0.x; w0.y = aB0.x; w0.z = aA0.y; w0.w = aB0.y;
        w1.x = aA0.z; w1.y = aB0.z; w1.z = aA0.w; w1.w = aB0.w;
        *(float4*)&dst[8 * t]     = w0;
        *(float4*)&dst[8 * t + 4] = w1;
        if (has2) {
            w0.x = aA1.x; w0.y = aB1.x; w0.z = aA1.y; w0.w = aB1.y;
            w1.x = aA1.z; w1.y = aB1.z; w1.z = aA1.w; w1.w = aB1.w;
            *(float4*)&dst[8 * (256 + t)]     = w0;
            *(float4*)&dst[8 * (256 + t) + 4] = w1;
        }
    }
    __syncthreads();                  // pair0 ready

    float* o0 = out + (size_t)b * C_DIM * hw + (size_t)y * W_DIM + x0 + t;
    float* o1 = o0 + (size_t)B_DIM * C_DIM * hw;

    // ---- main loop over 16 channel pairs:
    //      write(pair p+1) | issue load(pair p+2) | compute(pair p) ----
#pragma unroll
    for (int p = 0; p < NPAIR; ++p) {
        if (p + 1 < NPAIR) {                      // compile-time (full unroll)
            float* dst = sbuf[(p + 1) % 3];
            float4 w0, w1;
            w0.x = rA0.x; w0.y = rB0.x; w0.z = rA0.y; w0.w = rB0.y;
            w1.x = rA0.z; w1.y = rB0.z; w1.z = rA0.w; w1.w = rB0.w;
            *(float4*)&dst[8 * t]     = w0;
            *(float4*)&dst[8 * t + 4] = w1;
            if (has2) {
                w0.x = rA1.x; w0.y = rB1.x; w0.z = rA1.y; w0.w = rB1.y;
                w1.x = rA1.z; w1.y = rB1.z; w1.z = rA1.w; w1.w = rB1.w;
                *(float4*)&dst[8 * (256 + t)]     = w0;
                *(float4*)&dst[8 * (256 + t) + 4] = w1;
            }
        }
        float4 nA0, nB0, nA1, nB1;
        if (p + 2 < NPAIR) {
            const float* fn = fpl + (size_t)(2 * (p + 2)) * hw;
            nA0 = *(const float4*)(fn + soff0);
            nB0 = *(const float4*)(fn + hw + soff0);
            if (has2) {
                nA1 = *(const float4*)(fn + soff1);
                nB1 = *(const float4*)(fn + hw + soff1);
            }
        }

        // compute pair p: 15 ds_read_b64 taps (both channels per read)
        const float* src = sbuf[p % 3];
        float accA = 0.f, accB = 0.f;
#pragma unroll
        for (int s = 0; s < S_NUM; ++s) {
            const float2 v = *(const float2*)&src[2 * ldsoff[s]];
            accA = fmaf(v.x, wgt[s], accA);
            accB = fmaf(v.y, wgt[s], accB);
        }
        const float2 ctr = *(const float2*)&src[2 * (CTR_IDX + t)];

        o0[(size_t)(2 * p) * hw]     = accA;      // coalesced stores
        o0[(size_t)(2 * p + 1) * hw] = accB;
        o1[(size_t)(2 * p) * hw]     = ctr.x;
        o1[(size_t)(2 * p + 1) * hw] = ctr.y;

        if (p + 2 < NPAIR) {
            rA0 = nA0; rB0 = nB0;
            if (has2) { rA1 = nA1; rB1 = nB1; }
        }
        __syncthreads();                          // sbuf[(p+1)%3] ready
    }
}

extern "C" void kernel_launch(void* const* d_in, const int* in_sizes, int n_in,
                              void* d_out, int out_size, void* d_ws, size_t ws_size,
                              hipStream_t stream) {
    const float* depth      = (const float*)d_in[0];
    const float* features   = (const float*)d_in[1];
    const float* guide      = (const float*)d_in[2];
    const int*   sample_idx = (const int*)d_in[3];

    float* out = (float*)d_out;
    const int blocks = NPX / TX;  // 1024

    adaptive_fused_v12<<<blocks, 256, 0, stream>>>(depth, features, guide,
                                                   sample_idx, out);
}